// Round 1
// baseline (625.763 us; speedup 1.0000x reference)
//
#include <hip/hip_runtime.h>
#include <stdint.h>

// Sparse 3D avg-pool, kernel=stride=2, GRID=128, B=8, C=32.
// Keyspace = 8*64^3 = 2^21 -> dense histogram + scan instead of sort/unique.

#define KS (1u << 21)            // 2,097,152 possible keys
#define SCAN_BLOCKS 1024
#define SCAN_TPB 256
#define EPT 8                    // elems per thread: 256*8=2048/block, *1024 = 2^21
#define C 32

// ---- pass 1: key per voxel + dense histogram -------------------------------
__global__ void k_count(const int4* __restrict__ coords, uint32_t* __restrict__ keys,
                        uint32_t* __restrict__ cnt, int n) {
  int i = blockIdx.x * blockDim.x + threadIdx.x;
  if (i >= n) return;
  int4 cc = coords[i];  // (b, x, y, z)
  uint32_t k = (((uint32_t)cc.x * 64u + ((uint32_t)cc.y >> 1)) * 64u
                + ((uint32_t)cc.z >> 1)) * 64u + ((uint32_t)cc.w >> 1);
  keys[i] = k;
  atomicAdd(&cnt[k], 1u);
}

// ---- pass 2a: per-block sums of (presence, count) --------------------------
__global__ void k_blocksum(const uint32_t* __restrict__ cnt,
                           uint32_t* __restrict__ blkP, uint32_t* __restrict__ blkM) {
  __shared__ uint32_t sp[SCAN_TPB], sm[SCAN_TPB];
  int t = threadIdx.x;
  int base = blockIdx.x * (SCAN_TPB * EPT) + t * EPT;
  const uint4* c4 = (const uint4*)(cnt + base);
  uint4 q0 = c4[0], q1 = c4[1];
  uint32_t p = (q0.x > 0) + (q0.y > 0) + (q0.z > 0) + (q0.w > 0)
             + (q1.x > 0) + (q1.y > 0) + (q1.z > 0) + (q1.w > 0);
  uint32_t m = q0.x + q0.y + q0.z + q0.w + q1.x + q1.y + q1.z + q1.w;
  sp[t] = p; sm[t] = m;
  __syncthreads();
  for (int off = SCAN_TPB / 2; off > 0; off >>= 1) {
    if (t < off) { sp[t] += sp[t + off]; sm[t] += sm[t + off]; }
    __syncthreads();
  }
  if (t == 0) { blkP[blockIdx.x] = sp[0]; blkM[blockIdx.x] = sm[0]; }
}

// ---- pass 2b: exclusive scan of 1024 block sums (single block) -------------
__global__ void k_scan_blksums(uint32_t* __restrict__ blkP, uint32_t* __restrict__ blkM,
                               uint32_t* __restrict__ totalK) {
  __shared__ uint32_t sp[SCAN_BLOCKS], sm[SCAN_BLOCKS];
  int t = threadIdx.x;
  sp[t] = blkP[t]; sm[t] = blkM[t];
  __syncthreads();
  for (int off = 1; off < SCAN_BLOCKS; off <<= 1) {
    uint32_t vp = (t >= off) ? sp[t - off] : 0u;
    uint32_t vm = (t >= off) ? sm[t - off] : 0u;
    __syncthreads();
    sp[t] += vp; sm[t] += vm;
    __syncthreads();
  }
  blkP[t] = t ? sp[t - 1] : 0u;   // exclusive
  blkM[t] = t ? sm[t - 1] : 0u;
  if (t == SCAN_BLOCKS - 1) *totalK = sp[SCAN_BLOCKS - 1];
}

// ---- pass 2c: finalize per-key rank/start; emit uniq keys + cursors --------
__global__ void k_finalize(const uint32_t* __restrict__ cnt,
                           const uint32_t* __restrict__ blkP, const uint32_t* __restrict__ blkM,
                           uint32_t* __restrict__ cur,
                           uint32_t* __restrict__ denseStart, uint32_t* __restrict__ denseCnt,
                           float* __restrict__ uniqOut) {
  __shared__ uint32_t sp[SCAN_TPB], sm[SCAN_TPB];
  int t = threadIdx.x;
  int base = blockIdx.x * (SCAN_TPB * EPT) + t * EPT;
  const uint4* c4 = (const uint4*)(cnt + base);
  uint4 q0 = c4[0], q1 = c4[1];
  uint32_t c[EPT] = {q0.x, q0.y, q0.z, q0.w, q1.x, q1.y, q1.z, q1.w};
  uint32_t p = 0, m = 0;
#pragma unroll
  for (int e = 0; e < EPT; e++) { p += (c[e] > 0); m += c[e]; }
  sp[t] = p; sm[t] = m;
  __syncthreads();
  for (int off = 1; off < SCAN_TPB; off <<= 1) {
    uint32_t vp = (t >= off) ? sp[t - off] : 0u;
    uint32_t vm = (t >= off) ? sm[t - off] : 0u;
    __syncthreads();
    sp[t] += vp; sm[t] += vm;
    __syncthreads();
  }
  uint32_t poff = blkP[blockIdx.x] + (t ? sp[t - 1] : 0u);
  uint32_t moff = blkM[blockIdx.x] + (t ? sm[t - 1] : 0u);
#pragma unroll
  for (int e = 0; e < EPT; e++) {
    if (c[e] > 0) {
      uint32_t k = (uint32_t)base + (uint32_t)e;
      cur[k] = moff;                 // scatter cursor = group start
      denseStart[poff] = moff;
      denseCnt[poff]   = c[e];
      uniqOut[poff]    = (float)k;   // sorted unique key, exact in f32 (< 2^24)
      poff++;
    }
    moff += c[e];
  }
}

// ---- pass 3: counting-sort voxel indices by key -----------------------------
__global__ void k_scatter(const uint32_t* __restrict__ keys, uint32_t* __restrict__ cur,
                          uint32_t* __restrict__ sortedIdx, int n) {
  int i = blockIdx.x * blockDim.x + threadIdx.x;
  if (i >= n) return;
  uint32_t k = keys[i];
  uint32_t pos = atomicAdd(&cur[k], 1u);
  sortedIdx[pos] = (uint32_t)i;
}

// ---- uniq tail: -1 fill for padded slots ------------------------------------
__global__ void k_uniq_tail(float* __restrict__ uniqOut, const uint32_t* __restrict__ totalK,
                            int n) {
  int i = blockIdx.x * blockDim.x + threadIdx.x;
  uint32_t K = *totalK;
  if (i < n && (uint32_t)i >= K) uniqOut[i] = -1.0f;
}

// ---- pass 4: per-group mean; 32 lanes (half-wave) per output row ------------
__global__ void k_pool(const float* __restrict__ feats, const uint32_t* __restrict__ sortedIdx,
                       const uint32_t* __restrict__ denseStart, const uint32_t* __restrict__ denseCnt,
                       const uint32_t* __restrict__ totalK, float* __restrict__ outFeats, int n) {
  int lane = threadIdx.x & (C - 1);
  int j = blockIdx.x * (blockDim.x / C) + (threadIdx.x / C);
  if (j >= n) return;
  uint32_t K = *totalK;
  if ((uint32_t)j >= K) { outFeats[(size_t)j * C + lane] = 0.0f; return; }
  uint32_t s = denseStart[j];
  uint32_t c = denseCnt[j];
  float acc = 0.0f;
  for (uint32_t q = 0; q < c; q++) {
    uint32_t vi = sortedIdx[s + q];
    acc += feats[(size_t)vi * C + lane];   // 32 lanes -> contiguous 128B row
  }
  outFeats[(size_t)j * C + lane] = acc / (float)c;
}

extern "C" void kernel_launch(void* const* d_in, const int* in_sizes, int n_in,
                              void* d_out, int out_size, void* d_ws, size_t ws_size,
                              hipStream_t stream) {
  const float* feats = (const float*)d_in[0];
  const int4* coords = (const int4*)d_in[1];
  int n = in_sizes[0] / C;   // N = 2,000,000

  char* ws = (char*)d_ws;
  const size_t MB = 1024u * 1024u;
  uint32_t* keys       = (uint32_t*)(ws + 0 * MB);    // n u32   (8 MB)
  uint32_t* cnt        = (uint32_t*)(ws + 8 * MB);    // KS u32  (8 MB)
  uint32_t* cur        = (uint32_t*)(ws + 16 * MB);   // KS u32  (8 MB)
  uint32_t* denseStart = (uint32_t*)(ws + 24 * MB);   // <=n u32 (8 MB)
  uint32_t* denseCnt   = (uint32_t*)(ws + 32 * MB);   // <=n u32 (8 MB)
  uint32_t* sortedIdx  = (uint32_t*)(ws + 40 * MB);   // n u32   (8 MB)
  uint32_t* blkP       = (uint32_t*)(ws + 48 * MB);   // 1024 u32
  uint32_t* blkM       = blkP + SCAN_BLOCKS;          // 1024 u32
  uint32_t* totalK     = blkM + SCAN_BLOCKS;          // 1 u32

  float* outFeats = (float*)d_out;                    // [n, 32]
  float* uniqOut  = outFeats + (size_t)n * C;         // [n] keys as f32

  hipMemsetAsync(cnt, 0, KS * sizeof(uint32_t), stream);
  k_count<<<(n + 255) / 256, 256, 0, stream>>>(coords, keys, cnt, n);
  k_blocksum<<<SCAN_BLOCKS, SCAN_TPB, 0, stream>>>(cnt, blkP, blkM);
  k_scan_blksums<<<1, SCAN_BLOCKS, 0, stream>>>(blkP, blkM, totalK);
  k_finalize<<<SCAN_BLOCKS, SCAN_TPB, 0, stream>>>(cnt, blkP, blkM, cur, denseStart, denseCnt, uniqOut);
  k_scatter<<<(n + 255) / 256, 256, 0, stream>>>(keys, cur, sortedIdx, n);
  k_uniq_tail<<<(n + 255) / 256, 256, 0, stream>>>(uniqOut, totalK, n);
  k_pool<<<(n + 7) / 8, 256, 0, stream>>>(feats, sortedIdx, denseStart, denseCnt, totalK, outFeats, n);
}

// Round 2
// 507.651 us; speedup vs baseline: 1.2327x; 1.2327x over previous
//
#include <hip/hip_runtime.h>
#include <stdint.h>

// Sparse 3D avg-pool, kernel=stride=2, GRID=128, B=8, C=32.
// Keyspace = 8*64^3 = 2^21 -> dense histogram + scan instead of sort/unique.

#define KS (1u << 21)            // 2,097,152 possible keys
#define SCAN_BLOCKS 1024
#define SCAN_TPB 256
#define EPT 8                    // elems per thread: 256*8=2048/block, *1024 = 2^21
#define C 32

// ---- pass 1: key per voxel + dense histogram -------------------------------
__global__ void k_count(const int4* __restrict__ coords, uint32_t* __restrict__ keys,
                        uint32_t* __restrict__ cnt, int n) {
  int i = blockIdx.x * blockDim.x + threadIdx.x;
  if (i >= n) return;
  int4 cc = coords[i];  // (b, x, y, z)
  uint32_t k = (((uint32_t)cc.x * 64u + ((uint32_t)cc.y >> 1)) * 64u
                + ((uint32_t)cc.z >> 1)) * 64u + ((uint32_t)cc.w >> 1);
  keys[i] = k;
  atomicAdd(&cnt[k], 1u);
}

// ---- pass 2a: per-block sums of (presence, count) --------------------------
__global__ void k_blocksum(const uint32_t* __restrict__ cnt,
                           uint32_t* __restrict__ blkP, uint32_t* __restrict__ blkM) {
  __shared__ uint32_t sp[SCAN_TPB], sm[SCAN_TPB];
  int t = threadIdx.x;
  int base = blockIdx.x * (SCAN_TPB * EPT) + t * EPT;
  const uint4* c4 = (const uint4*)(cnt + base);
  uint4 q0 = c4[0], q1 = c4[1];
  uint32_t p = (q0.x > 0) + (q0.y > 0) + (q0.z > 0) + (q0.w > 0)
             + (q1.x > 0) + (q1.y > 0) + (q1.z > 0) + (q1.w > 0);
  uint32_t m = q0.x + q0.y + q0.z + q0.w + q1.x + q1.y + q1.z + q1.w;
  sp[t] = p; sm[t] = m;
  __syncthreads();
  for (int off = SCAN_TPB / 2; off > 0; off >>= 1) {
    if (t < off) { sp[t] += sp[t + off]; sm[t] += sm[t + off]; }
    __syncthreads();
  }
  if (t == 0) { blkP[blockIdx.x] = sp[0]; blkM[blockIdx.x] = sm[0]; }
}

// ---- pass 2b: exclusive scan of 1024 block sums (single block) -------------
__global__ void k_scan_blksums(uint32_t* __restrict__ blkP, uint32_t* __restrict__ blkM,
                               uint32_t* __restrict__ totalK) {
  __shared__ uint32_t sp[SCAN_BLOCKS], sm[SCAN_BLOCKS];
  int t = threadIdx.x;
  sp[t] = blkP[t]; sm[t] = blkM[t];
  __syncthreads();
  for (int off = 1; off < SCAN_BLOCKS; off <<= 1) {
    uint32_t vp = (t >= off) ? sp[t - off] : 0u;
    uint32_t vm = (t >= off) ? sm[t - off] : 0u;
    __syncthreads();
    sp[t] += vp; sm[t] += vm;
    __syncthreads();
  }
  blkP[t] = t ? sp[t - 1] : 0u;   // exclusive
  blkM[t] = t ? sm[t - 1] : 0u;
  if (t == SCAN_BLOCKS - 1) *totalK = sp[SCAN_BLOCKS - 1];
}

// ---- pass 2c: finalize per-key rank/start; emit uniq keys + cursors --------
__global__ void k_finalize(const uint32_t* __restrict__ cnt,
                           const uint32_t* __restrict__ blkP, const uint32_t* __restrict__ blkM,
                           uint32_t* __restrict__ cur,
                           uint32_t* __restrict__ denseStart, uint32_t* __restrict__ denseCnt,
                           float* __restrict__ uniqOut) {
  __shared__ uint32_t sp[SCAN_TPB], sm[SCAN_TPB];
  int t = threadIdx.x;
  int base = blockIdx.x * (SCAN_TPB * EPT) + t * EPT;
  const uint4* c4 = (const uint4*)(cnt + base);
  uint4 q0 = c4[0], q1 = c4[1];
  uint32_t c[EPT] = {q0.x, q0.y, q0.z, q0.w, q1.x, q1.y, q1.z, q1.w};
  uint32_t p = 0, m = 0;
#pragma unroll
  for (int e = 0; e < EPT; e++) { p += (c[e] > 0); m += c[e]; }
  sp[t] = p; sm[t] = m;
  __syncthreads();
  for (int off = 1; off < SCAN_TPB; off <<= 1) {
    uint32_t vp = (t >= off) ? sp[t - off] : 0u;
    uint32_t vm = (t >= off) ? sm[t - off] : 0u;
    __syncthreads();
    sp[t] += vp; sm[t] += vm;
    __syncthreads();
  }
  uint32_t poff = blkP[blockIdx.x] + (t ? sp[t - 1] : 0u);
  uint32_t moff = blkM[blockIdx.x] + (t ? sm[t - 1] : 0u);
#pragma unroll
  for (int e = 0; e < EPT; e++) {
    if (c[e] > 0) {
      uint32_t k = (uint32_t)base + (uint32_t)e;
      cur[k] = moff;                 // scatter cursor = group start
      denseStart[poff] = moff;
      denseCnt[poff]   = c[e];
      uniqOut[poff]    = (float)k;   // sorted unique key, exact in f32 (< 2^24)
      poff++;
    }
    moff += c[e];
  }
}

// ---- pass 3: counting-sort voxel indices by key -----------------------------
__global__ void k_scatter(const uint32_t* __restrict__ keys, uint32_t* __restrict__ cur,
                          uint32_t* __restrict__ sortedIdx, int n) {
  int i = blockIdx.x * blockDim.x + threadIdx.x;
  if (i >= n) return;
  uint32_t k = keys[i];
  uint32_t pos = atomicAdd(&cur[k], 1u);
  sortedIdx[pos] = (uint32_t)i;
}

// ---- uniq tail: -1 fill for padded slots ------------------------------------
__global__ void k_uniq_tail(float* __restrict__ uniqOut, const uint32_t* __restrict__ totalK,
                            int n) {
  int i = blockIdx.x * blockDim.x + threadIdx.x;
  uint32_t K = *totalK;
  if (i < n && (uint32_t)i >= K) uniqOut[i] = -1.0f;
}

// ---- pass 4: per-group mean; 32 lanes per row, 2 rows per half-wave --------
// MLP-optimized: lane-parallel index prefetch + shfl broadcast, 2 rows
// interleaved + 2-deep unroll -> up to 4 independent feats gathers in flight.
__global__ __launch_bounds__(256, 8)
void k_pool(const float* __restrict__ feats, const uint32_t* __restrict__ sortedIdx,
            const uint32_t* __restrict__ denseStart, const uint32_t* __restrict__ denseCnt,
            const uint32_t* __restrict__ totalK, float* __restrict__ outFeats, int n) {
  const int lane = threadIdx.x & (C - 1);
  const int half = threadIdx.x >> 5;          // 0..7
  const uint32_t K = *totalK;
  const int jb = blockIdx.x * 16;
  const int j0 = jb + half;
  const int j1 = jb + 8 + half;

  const bool v0 = j0 < n, v1 = j1 < n;
  const bool r0 = v0 && (uint32_t)j0 < K;
  const bool r1 = v1 && (uint32_t)j1 < K;

  uint32_t s0 = 0, c0 = 0, s1 = 0, c1 = 0;
  if (r0) { s0 = denseStart[j0]; c0 = denseCnt[j0]; }
  if (r1) { s1 = denseStart[j1]; c1 = denseCnt[j1]; }

  // lane-parallel contiguous prefetch of group indices (coalesced)
  uint32_t i0 = 0, i1 = 0;
  if (r0 && (uint32_t)lane < c0) i0 = sortedIdx[s0 + (uint32_t)lane];
  if (r1 && (uint32_t)lane < c1) i1 = sortedIdx[s1 + (uint32_t)lane];

  const uint32_t m0 = c0 < 32u ? c0 : 32u;
  const uint32_t m1 = c1 < 32u ? c1 : 32u;
  const uint32_t mm = m0 > m1 ? m0 : m1;

  float a0 = 0.f, a1 = 0.f, b0 = 0.f, b1 = 0.f;
  uint32_t q = 0;
  for (; q + 2 <= mm; q += 2) {
    uint32_t u00 = __shfl(i0, (int)q, 32);
    uint32_t u01 = __shfl(i0, (int)q + 1, 32);
    uint32_t u10 = __shfl(i1, (int)q, 32);
    uint32_t u11 = __shfl(i1, (int)q + 1, 32);
    if (q     < m0) a0 += feats[(size_t)u00 * C + lane];
    if (q     < m1) a1 += feats[(size_t)u10 * C + lane];
    if (q + 1 < m0) b0 += feats[(size_t)u01 * C + lane];
    if (q + 1 < m1) b1 += feats[(size_t)u11 * C + lane];
  }
  if (q < mm) {
    uint32_t u00 = __shfl(i0, (int)q, 32);
    uint32_t u10 = __shfl(i1, (int)q, 32);
    if (q < m0) a0 += feats[(size_t)u00 * C + lane];
    if (q < m1) a1 += feats[(size_t)u10 * C + lane];
  }
  // ultra-rare overflow (group larger than 32)
  for (uint32_t qq = 32; qq < c0; ++qq) a0 += feats[(size_t)sortedIdx[s0 + qq] * C + lane];
  for (uint32_t qq = 32; qq < c1; ++qq) a1 += feats[(size_t)sortedIdx[s1 + qq] * C + lane];
  a0 += b0; a1 += b1;

  if (v0) {
    float o = r0 ? a0 / (float)c0 : 0.f;
    __builtin_nontemporal_store(o, &outFeats[(size_t)j0 * C + lane]);
  }
  if (v1) {
    float o = r1 ? a1 / (float)c1 : 0.f;
    __builtin_nontemporal_store(o, &outFeats[(size_t)j1 * C + lane]);
  }
}

extern "C" void kernel_launch(void* const* d_in, const int* in_sizes, int n_in,
                              void* d_out, int out_size, void* d_ws, size_t ws_size,
                              hipStream_t stream) {
  const float* feats = (const float*)d_in[0];
  const int4* coords = (const int4*)d_in[1];
  int n = in_sizes[0] / C;   // N = 2,000,000

  char* ws = (char*)d_ws;
  const size_t MB = 1024u * 1024u;
  uint32_t* keys       = (uint32_t*)(ws + 0 * MB);    // n u32   (8 MB)
  uint32_t* cnt        = (uint32_t*)(ws + 8 * MB);    // KS u32  (8 MB)
  uint32_t* cur        = (uint32_t*)(ws + 16 * MB);   // KS u32  (8 MB)
  uint32_t* denseStart = (uint32_t*)(ws + 24 * MB);   // <=n u32 (8 MB)
  uint32_t* denseCnt   = (uint32_t*)(ws + 32 * MB);   // <=n u32 (8 MB)
  uint32_t* sortedIdx  = (uint32_t*)(ws + 40 * MB);   // n u32   (8 MB)
  uint32_t* blkP       = (uint32_t*)(ws + 48 * MB);   // 1024 u32
  uint32_t* blkM       = blkP + SCAN_BLOCKS;          // 1024 u32
  uint32_t* totalK     = blkM + SCAN_BLOCKS;          // 1 u32

  float* outFeats = (float*)d_out;                    // [n, 32]
  float* uniqOut  = outFeats + (size_t)n * C;         // [n] keys as f32

  hipMemsetAsync(cnt, 0, KS * sizeof(uint32_t), stream);
  k_count<<<(n + 255) / 256, 256, 0, stream>>>(coords, keys, cnt, n);
  k_blocksum<<<SCAN_BLOCKS, SCAN_TPB, 0, stream>>>(cnt, blkP, blkM);
  k_scan_blksums<<<1, SCAN_BLOCKS, 0, stream>>>(blkP, blkM, totalK);
  k_finalize<<<SCAN_BLOCKS, SCAN_TPB, 0, stream>>>(cnt, blkP, blkM, cur, denseStart, denseCnt, uniqOut);
  k_scatter<<<(n + 255) / 256, 256, 0, stream>>>(keys, cur, sortedIdx, n);
  k_uniq_tail<<<(n + 255) / 256, 256, 0, stream>>>(uniqOut, totalK, n);
  k_pool<<<(n + 15) / 16, 256, 0, stream>>>(feats, sortedIdx, denseStart, denseCnt, totalK, outFeats, n);
}

// Round 3
// 304.176 us; speedup vs baseline: 2.0572x; 1.6689x over previous
//
#include <hip/hip_runtime.h>
#include <stdint.h>

// Sparse 3D avg-pool, kernel=stride=2, GRID=128, B=8, C=32.
// Keyspace = 8*64^3 = 2^21 -> dense histogram + scan instead of sort/unique.
// Round 3: deep-MLP k_pool (4 rows/half-wave, 16 unconditional masked gathers),
// rank packed in key high bits -> atomic-free scatter.

#define KS (1u << 21)            // 2,097,152 possible keys
#define KMASK (KS - 1u)
#define SCAN_BLOCKS 1024
#define SCAN_TPB 256
#define EPT 8                    // elems per thread: 256*8=2048/block, *1024 = 2^21
#define C 32

// ---- pass 1: key per voxel + dense histogram; rank packed in key bits ------
__global__ void k_count(const int4* __restrict__ coords, uint32_t* __restrict__ keys,
                        uint32_t* __restrict__ cnt, int n) {
  int i = blockIdx.x * blockDim.x + threadIdx.x;
  if (i >= n) return;
  int4 cc = coords[i];  // (b, x, y, z)
  uint32_t k = (((uint32_t)cc.x * 64u + ((uint32_t)cc.y >> 1)) * 64u
                + ((uint32_t)cc.z >> 1)) * 64u + ((uint32_t)cc.w >> 1);
  uint32_t r = atomicAdd(&cnt[k], 1u);   // arrival rank within group (< 2^11 for this data)
  keys[i] = k | (r << 21);
}

// ---- pass 2a: per-block sums of (presence, count) --------------------------
__global__ void k_blocksum(const uint32_t* __restrict__ cnt,
                           uint32_t* __restrict__ blkP, uint32_t* __restrict__ blkM) {
  __shared__ uint32_t sp[SCAN_TPB], sm[SCAN_TPB];
  int t = threadIdx.x;
  int base = blockIdx.x * (SCAN_TPB * EPT) + t * EPT;
  const uint4* c4 = (const uint4*)(cnt + base);
  uint4 q0 = c4[0], q1 = c4[1];
  uint32_t p = (q0.x > 0) + (q0.y > 0) + (q0.z > 0) + (q0.w > 0)
             + (q1.x > 0) + (q1.y > 0) + (q1.z > 0) + (q1.w > 0);
  uint32_t m = q0.x + q0.y + q0.z + q0.w + q1.x + q1.y + q1.z + q1.w;
  sp[t] = p; sm[t] = m;
  __syncthreads();
  for (int off = SCAN_TPB / 2; off > 0; off >>= 1) {
    if (t < off) { sp[t] += sp[t + off]; sm[t] += sm[t + off]; }
    __syncthreads();
  }
  if (t == 0) { blkP[blockIdx.x] = sp[0]; blkM[blockIdx.x] = sm[0]; }
}

// ---- pass 2b: exclusive scan of 1024 block sums (single block) -------------
__global__ void k_scan_blksums(uint32_t* __restrict__ blkP, uint32_t* __restrict__ blkM,
                               uint32_t* __restrict__ totalK) {
  __shared__ uint32_t sp[SCAN_BLOCKS], sm[SCAN_BLOCKS];
  int t = threadIdx.x;
  sp[t] = blkP[t]; sm[t] = blkM[t];
  __syncthreads();
  for (int off = 1; off < SCAN_BLOCKS; off <<= 1) {
    uint32_t vp = (t >= off) ? sp[t - off] : 0u;
    uint32_t vm = (t >= off) ? sm[t - off] : 0u;
    __syncthreads();
    sp[t] += vp; sm[t] += vm;
    __syncthreads();
  }
  blkP[t] = t ? sp[t - 1] : 0u;   // exclusive
  blkM[t] = t ? sm[t - 1] : 0u;
  if (t == SCAN_BLOCKS - 1) *totalK = sp[SCAN_BLOCKS - 1];
}

// ---- pass 2c: finalize per-key rank/start; emit uniq keys + group starts ---
__global__ void k_finalize(const uint32_t* __restrict__ cnt,
                           const uint32_t* __restrict__ blkP, const uint32_t* __restrict__ blkM,
                           uint32_t* __restrict__ cur,
                           uint32_t* __restrict__ denseStart, uint32_t* __restrict__ denseCnt,
                           float* __restrict__ uniqOut) {
  __shared__ uint32_t sp[SCAN_TPB], sm[SCAN_TPB];
  int t = threadIdx.x;
  int base = blockIdx.x * (SCAN_TPB * EPT) + t * EPT;
  const uint4* c4 = (const uint4*)(cnt + base);
  uint4 q0 = c4[0], q1 = c4[1];
  uint32_t c[EPT] = {q0.x, q0.y, q0.z, q0.w, q1.x, q1.y, q1.z, q1.w};
  uint32_t p = 0, m = 0;
#pragma unroll
  for (int e = 0; e < EPT; e++) { p += (c[e] > 0); m += c[e]; }
  sp[t] = p; sm[t] = m;
  __syncthreads();
  for (int off = 1; off < SCAN_TPB; off <<= 1) {
    uint32_t vp = (t >= off) ? sp[t - off] : 0u;
    uint32_t vm = (t >= off) ? sm[t - off] : 0u;
    __syncthreads();
    sp[t] += vp; sm[t] += vm;
    __syncthreads();
  }
  uint32_t poff = blkP[blockIdx.x] + (t ? sp[t - 1] : 0u);
  uint32_t moff = blkM[blockIdx.x] + (t ? sm[t - 1] : 0u);
#pragma unroll
  for (int e = 0; e < EPT; e++) {
    if (c[e] > 0) {
      uint32_t k = (uint32_t)base + (uint32_t)e;
      cur[k] = moff;                 // group start (read-only downstream)
      denseStart[poff] = moff;
      denseCnt[poff]   = c[e];
      uniqOut[poff]    = (float)k;   // sorted unique key, exact in f32 (< 2^24)
      poff++;
    }
    moff += c[e];
  }
}

// ---- pass 3: atomic-free counting-sort placement ----------------------------
__global__ void k_scatter(const uint32_t* __restrict__ keys, const uint32_t* __restrict__ cur,
                          uint32_t* __restrict__ sortedIdx, int n) {
  int i = blockIdx.x * blockDim.x + threadIdx.x;
  if (i >= n) return;
  uint32_t kk = keys[i];
  uint32_t pos = cur[kk & KMASK] + (kk >> 21);
  sortedIdx[pos] = (uint32_t)i;
}

// ---- uniq tail: -1 fill for padded slots ------------------------------------
__global__ void k_uniq_tail(float* __restrict__ uniqOut, const uint32_t* __restrict__ totalK,
                            int n) {
  int i = blockIdx.x * blockDim.x + threadIdx.x;
  uint32_t K = *totalK;
  if (i < n && (uint32_t)i >= K) uniqOut[i] = -1.0f;
}

// ---- pass 4: per-group mean; 4 rows per half-wave, 16 masked gathers -------
__global__ __launch_bounds__(256, 8)
void k_pool(const float* __restrict__ feats, const uint32_t* __restrict__ sortedIdx,
            const uint32_t* __restrict__ denseStart, const uint32_t* __restrict__ denseCnt,
            const uint32_t* __restrict__ totalK, float* __restrict__ outFeats, int n) {
  const int lane = threadIdx.x & 31;
  const int hw = threadIdx.x >> 5;            // 0..7
  const uint32_t K = *totalK;
  const int jb = blockIdx.x * 32 + hw;        // rows jb + {0,8,16,24}

  uint32_t s[4], c[4], idx[4];
  float acc[4];
#pragma unroll
  for (int r = 0; r < 4; ++r) {
    int j = jb + r * 8;
    bool live = (j < n) && ((uint32_t)j < K);
    s[r] = live ? denseStart[j] : 0u;
    c[r] = live ? denseCnt[j] : 0u;
    idx[r] = 0u;
    if (live && (uint32_t)lane < c[r]) idx[r] = sortedIdx[s[r] + (uint32_t)lane];
    acc[r] = 0.f;
  }
  // 16 independent masked gathers: invalid -> feats row 0 (L1 broadcast), masked add.
#pragma unroll
  for (int q = 0; q < 4; ++q) {
#pragma unroll
    for (int r = 0; r < 4; ++r) {
      uint32_t u = (uint32_t)__shfl((int)idx[r], q, 32);
      float v = feats[(size_t)u * C + lane];
      acc[r] += ((uint32_t)q < c[r]) ? v : 0.f;
    }
  }
  // rare tails (c > 4): ~0.3% of rows
#pragma unroll
  for (int r = 0; r < 4; ++r) {
    for (uint32_t q = 4; q < c[r]; ++q) {
      uint32_t u = (q < 32u) ? (uint32_t)__shfl((int)idx[r], (int)q, 32)
                             : sortedIdx[s[r] + q];
      acc[r] += feats[(size_t)u * C + lane];
    }
  }
#pragma unroll
  for (int r = 0; r < 4; ++r) {
    int j = jb + r * 8;
    if (j < n) {
      bool live = (uint32_t)j < K;
      float o = live ? acc[r] / (float)c[r] : 0.f;
      __builtin_nontemporal_store(o, &outFeats[(size_t)j * C + lane]);
    }
  }
}

extern "C" void kernel_launch(void* const* d_in, const int* in_sizes, int n_in,
                              void* d_out, int out_size, void* d_ws, size_t ws_size,
                              hipStream_t stream) {
  const float* feats = (const float*)d_in[0];
  const int4* coords = (const int4*)d_in[1];
  int n = in_sizes[0] / C;   // N = 2,000,000

  char* ws = (char*)d_ws;
  const size_t MB = 1024u * 1024u;
  uint32_t* keys       = (uint32_t*)(ws + 0 * MB);    // n u32   (8 MB) key|rank<<21
  uint32_t* cnt        = (uint32_t*)(ws + 8 * MB);    // KS u32  (8 MB)
  uint32_t* cur        = (uint32_t*)(ws + 16 * MB);   // KS u32  (8 MB) group starts
  uint32_t* denseStart = (uint32_t*)(ws + 24 * MB);   // <=n u32 (8 MB)
  uint32_t* denseCnt   = (uint32_t*)(ws + 32 * MB);   // <=n u32 (8 MB)
  uint32_t* sortedIdx  = (uint32_t*)(ws + 40 * MB);   // n u32   (8 MB)
  uint32_t* blkP       = (uint32_t*)(ws + 48 * MB);   // 1024 u32
  uint32_t* blkM       = blkP + SCAN_BLOCKS;          // 1024 u32
  uint32_t* totalK     = blkM + SCAN_BLOCKS;          // 1 u32

  float* outFeats = (float*)d_out;                    // [n, 32]
  float* uniqOut  = outFeats + (size_t)n * C;         // [n] keys as f32

  hipMemsetAsync(cnt, 0, KS * sizeof(uint32_t), stream);
  k_count<<<(n + 255) / 256, 256, 0, stream>>>(coords, keys, cnt, n);
  k_blocksum<<<SCAN_BLOCKS, SCAN_TPB, 0, stream>>>(cnt, blkP, blkM);
  k_scan_blksums<<<1, SCAN_BLOCKS, 0, stream>>>(blkP, blkM, totalK);
  k_finalize<<<SCAN_BLOCKS, SCAN_TPB, 0, stream>>>(cnt, blkP, blkM, cur, denseStart, denseCnt, uniqOut);
  k_scatter<<<(n + 255) / 256, 256, 0, stream>>>(keys, cur, sortedIdx, n);
  k_uniq_tail<<<(n + 255) / 256, 256, 0, stream>>>(uniqOut, totalK, n);
  k_pool<<<(n + 31) / 32, 256, 0, stream>>>(feats, sortedIdx, denseStart, denseCnt, totalK, outFeats, n);
}

// Round 4
// 278.469 us; speedup vs baseline: 2.2472x; 1.0923x over previous
//
#include <hip/hip_runtime.h>
#include <stdint.h>

// Sparse 3D avg-pool, kernel=stride=2, GRID=128, B=8, C=32.
// Keyspace = 8*64^3 = 2^21 -> dense histogram + scan instead of sort/unique.
// Round 4: float4-lane k_pool (half-wave = 4 consecutive rows x 8 lanes x float4);
// one dwordx4 gather serves 4 rows -> ~4x fewer vmem instructions, coalesced stores.
// uniq tail folded into k_pool; meta packed u64.

#define KS (1u << 21)            // 2,097,152 possible keys
#define KMASK (KS - 1u)
#define SCAN_BLOCKS 1024
#define SCAN_TPB 256
#define EPT 8                    // elems per thread: 256*8=2048/block, *1024 = 2^21
#define C 32

typedef float vf4 __attribute__((ext_vector_type(4)));

// ---- pass 1: key per voxel + dense histogram; rank packed in key bits ------
__global__ void k_count(const int4* __restrict__ coords, uint32_t* __restrict__ keys,
                        uint32_t* __restrict__ cnt, int n) {
  int i = blockIdx.x * blockDim.x + threadIdx.x;
  if (i >= n) return;
  int4 cc = coords[i];  // (b, x, y, z)
  uint32_t k = (((uint32_t)cc.x * 64u + ((uint32_t)cc.y >> 1)) * 64u
                + ((uint32_t)cc.z >> 1)) * 64u + ((uint32_t)cc.w >> 1);
  uint32_t r = atomicAdd(&cnt[k], 1u);   // arrival rank within group (small for this data)
  keys[i] = k | (r << 21);
}

// ---- pass 2a: per-block sums of (presence, count) --------------------------
__global__ void k_blocksum(const uint32_t* __restrict__ cnt,
                           uint32_t* __restrict__ blkP, uint32_t* __restrict__ blkM) {
  __shared__ uint32_t sp[SCAN_TPB], sm[SCAN_TPB];
  int t = threadIdx.x;
  int base = blockIdx.x * (SCAN_TPB * EPT) + t * EPT;
  const uint4* c4 = (const uint4*)(cnt + base);
  uint4 q0 = c4[0], q1 = c4[1];
  uint32_t p = (q0.x > 0) + (q0.y > 0) + (q0.z > 0) + (q0.w > 0)
             + (q1.x > 0) + (q1.y > 0) + (q1.z > 0) + (q1.w > 0);
  uint32_t m = q0.x + q0.y + q0.z + q0.w + q1.x + q1.y + q1.z + q1.w;
  sp[t] = p; sm[t] = m;
  __syncthreads();
  for (int off = SCAN_TPB / 2; off > 0; off >>= 1) {
    if (t < off) { sp[t] += sp[t + off]; sm[t] += sm[t + off]; }
    __syncthreads();
  }
  if (t == 0) { blkP[blockIdx.x] = sp[0]; blkM[blockIdx.x] = sm[0]; }
}

// ---- pass 2b: exclusive scan of 1024 block sums (single block) -------------
__global__ void k_scan_blksums(uint32_t* __restrict__ blkP, uint32_t* __restrict__ blkM,
                               uint32_t* __restrict__ totalK) {
  __shared__ uint32_t sp[SCAN_BLOCKS], sm[SCAN_BLOCKS];
  int t = threadIdx.x;
  sp[t] = blkP[t]; sm[t] = blkM[t];
  __syncthreads();
  for (int off = 1; off < SCAN_BLOCKS; off <<= 1) {
    uint32_t vp = (t >= off) ? sp[t - off] : 0u;
    uint32_t vm = (t >= off) ? sm[t - off] : 0u;
    __syncthreads();
    sp[t] += vp; sm[t] += vm;
    __syncthreads();
  }
  blkP[t] = t ? sp[t - 1] : 0u;   // exclusive
  blkM[t] = t ? sm[t - 1] : 0u;
  if (t == SCAN_BLOCKS - 1) *totalK = sp[SCAN_BLOCKS - 1];
}

// ---- pass 2c: finalize per-key rank/start; emit uniq keys + packed meta ----
__global__ void k_finalize(const uint32_t* __restrict__ cnt,
                           const uint32_t* __restrict__ blkP, const uint32_t* __restrict__ blkM,
                           uint32_t* __restrict__ cur,
                           uint64_t* __restrict__ denseMeta,
                           float* __restrict__ uniqOut) {
  __shared__ uint32_t sp[SCAN_TPB], sm[SCAN_TPB];
  int t = threadIdx.x;
  int base = blockIdx.x * (SCAN_TPB * EPT) + t * EPT;
  const uint4* c4 = (const uint4*)(cnt + base);
  uint4 q0 = c4[0], q1 = c4[1];
  uint32_t c[EPT] = {q0.x, q0.y, q0.z, q0.w, q1.x, q1.y, q1.z, q1.w};
  uint32_t p = 0, m = 0;
#pragma unroll
  for (int e = 0; e < EPT; e++) { p += (c[e] > 0); m += c[e]; }
  sp[t] = p; sm[t] = m;
  __syncthreads();
  for (int off = 1; off < SCAN_TPB; off <<= 1) {
    uint32_t vp = (t >= off) ? sp[t - off] : 0u;
    uint32_t vm = (t >= off) ? sm[t - off] : 0u;
    __syncthreads();
    sp[t] += vp; sm[t] += vm;
    __syncthreads();
  }
  uint32_t poff = blkP[blockIdx.x] + (t ? sp[t - 1] : 0u);
  uint32_t moff = blkM[blockIdx.x] + (t ? sm[t - 1] : 0u);
#pragma unroll
  for (int e = 0; e < EPT; e++) {
    if (c[e] > 0) {
      uint32_t k = (uint32_t)base + (uint32_t)e;
      cur[k] = moff;                               // group start (read-only downstream)
      denseMeta[poff] = ((uint64_t)c[e] << 32) | (uint64_t)moff;
      uniqOut[poff]   = (float)k;                  // sorted unique key, exact in f32
      poff++;
    }
    moff += c[e];
  }
}

// ---- pass 3: atomic-free counting-sort placement ----------------------------
__global__ void k_scatter(const uint32_t* __restrict__ keys, const uint32_t* __restrict__ cur,
                          uint32_t* __restrict__ sortedIdx, int n) {
  int i = blockIdx.x * blockDim.x + threadIdx.x;
  if (i >= n) return;
  uint32_t kk = keys[i];
  uint32_t pos = cur[kk & KMASK] + (kk >> 21);
  sortedIdx[pos] = (uint32_t)i;
}

// ---- pass 4: per-group mean; half-wave = 4 consecutive rows x 8 lanes x f4 --
__global__ __launch_bounds__(256, 8)
void k_pool(const float* __restrict__ feats, const uint32_t* __restrict__ sortedIdx,
            const uint64_t* __restrict__ denseMeta, const uint32_t* __restrict__ totalK,
            float* __restrict__ outFeats, float* __restrict__ uniqOut, int n) {
  const int tid = threadIdx.x;
  const int hw = tid >> 5;              // half-wave 0..7
  const int lane = tid & 31;
  const int subrow = lane >> 3;         // 0..3: which of 4 consecutive rows
  const int cl = lane & 7;              // float4 column within the 32-ch row
  const uint32_t K = *totalK;
  const int j = (blockIdx.x * 8 + hw) * 4 + subrow;
  const bool valid = j < n;
  const bool live = valid && ((uint32_t)j < K);

  uint32_t s_sub = 0, c_sub = 0;
  if (live) {
    uint64_t dm = denseMeta[j];         // 8 lanes same addr -> broadcast
    s_sub = (uint32_t)dm;
    c_sub = (uint32_t)(dm >> 32);
  }
  uint32_t midx = 0;                    // member cl of my row (up to 8 prefetched)
  if (live && (uint32_t)cl < c_sub) midx = sortedIdx[s_sub + (uint32_t)cl];

  vf4 acc = {0.f, 0.f, 0.f, 0.f};
  // 4 fixed slots: one dwordx4 gather per slot serves all 4 rows (4 cache lines).
#pragma unroll
  for (int q = 0; q < 4; ++q) {
    uint32_t u = (uint32_t)__shfl((int)midx, (subrow << 3) | q, 32);
    vf4 v = *(const vf4*)(feats + (size_t)u * C + cl * 4);
    if ((uint32_t)q < c_sub) acc += v;
  }
  // tail to c<=8 (~0.45% of rows): wave-uniform early exit
  for (uint32_t q = 4; q < 8u; ++q) {
    if (__all((int)(q >= c_sub))) break;
    uint32_t u = (uint32_t)__shfl((int)midx, (int)(((uint32_t)subrow << 3) | q), 32);
    vf4 v = *(const vf4*)(feats + (size_t)u * C + cl * 4);
    if (q < c_sub) acc += v;
  }
  // essentially-never fallback for c>8
  if (__any((int)(c_sub > 8u))) {
    for (uint32_t q = 8; q < c_sub; ++q) {
      uint32_t u = sortedIdx[s_sub + q];
      acc += *(const vf4*)(feats + (size_t)u * C + cl * 4);
    }
  }

  if (valid) {
    float invc = live ? 1.0f / (float)c_sub : 0.0f;
    vf4 o = acc * invc;
    __builtin_nontemporal_store(o, (vf4*)(outFeats + (size_t)j * C + cl * 4));
    if (!live && cl == 0) uniqOut[j] = -1.0f;   // folded-in uniq tail
  }
}

extern "C" void kernel_launch(void* const* d_in, const int* in_sizes, int n_in,
                              void* d_out, int out_size, void* d_ws, size_t ws_size,
                              hipStream_t stream) {
  const float* feats = (const float*)d_in[0];
  const int4* coords = (const int4*)d_in[1];
  int n = in_sizes[0] / C;   // N = 2,000,000

  char* ws = (char*)d_ws;
  const size_t MB = 1024u * 1024u;
  uint32_t* keys      = (uint32_t*)(ws + 0 * MB);    // n u32   (8 MB) key|rank<<21
  uint32_t* cnt       = (uint32_t*)(ws + 8 * MB);    // KS u32  (8 MB)
  uint32_t* cur       = (uint32_t*)(ws + 16 * MB);   // KS u32  (8 MB) group starts
  uint64_t* denseMeta = (uint64_t*)(ws + 24 * MB);   // <=n u64 (16 MB) {cnt,start}
  uint32_t* sortedIdx = (uint32_t*)(ws + 40 * MB);   // n u32   (8 MB)
  uint32_t* blkP      = (uint32_t*)(ws + 48 * MB);   // 1024 u32
  uint32_t* blkM      = blkP + SCAN_BLOCKS;          // 1024 u32
  uint32_t* totalK    = blkM + SCAN_BLOCKS;          // 1 u32

  float* outFeats = (float*)d_out;                   // [n, 32]
  float* uniqOut  = outFeats + (size_t)n * C;        // [n] keys as f32

  hipMemsetAsync(cnt, 0, KS * sizeof(uint32_t), stream);
  k_count<<<(n + 255) / 256, 256, 0, stream>>>(coords, keys, cnt, n);
  k_blocksum<<<SCAN_BLOCKS, SCAN_TPB, 0, stream>>>(cnt, blkP, blkM);
  k_scan_blksums<<<1, SCAN_BLOCKS, 0, stream>>>(blkP, blkM, totalK);
  k_finalize<<<SCAN_BLOCKS, SCAN_TPB, 0, stream>>>(cnt, blkP, blkM, cur, denseMeta, uniqOut);
  k_scatter<<<(n + 255) / 256, 256, 0, stream>>>(keys, cur, sortedIdx, n);
  k_pool<<<(n + 31) / 32, 256, 0, stream>>>(feats, sortedIdx, denseMeta, totalK, outFeats, uniqOut, n);
}

// Round 5
// 277.672 us; speedup vs baseline: 2.2536x; 1.0029x over previous
//
#include <hip/hip_runtime.h>
#include <stdint.h>

// Sparse 3D avg-pool, kernel=stride=2, GRID=128, B=8, C=32.
// Keyspace = 8*64^3 = 2^21 -> dense histogram + scan instead of sort/unique.
// Round 5: own k_zero (no rocclr fillBuffer), k_pool slot-0 unconditional +
// wave-uniform early exit for slots 1..7.

#define KS (1u << 21)            // 2,097,152 possible keys
#define KMASK (KS - 1u)
#define SCAN_BLOCKS 1024
#define SCAN_TPB 256
#define EPT 8                    // elems per thread: 256*8=2048/block, *1024 = 2^21
#define C 32

typedef float vf4 __attribute__((ext_vector_type(4)));

// ---- pass 0: zero the histogram (replaces hipMemsetAsync/rocclr fill) ------
__global__ void k_zero(uint4* __restrict__ p, int n4) {
  int i = blockIdx.x * blockDim.x + threadIdx.x;
  if (i < n4) p[i] = make_uint4(0u, 0u, 0u, 0u);
}

// ---- pass 1: key per voxel + dense histogram; rank packed in key bits ------
__global__ void k_count(const int4* __restrict__ coords, uint32_t* __restrict__ keys,
                        uint32_t* __restrict__ cnt, int n) {
  int i = blockIdx.x * blockDim.x + threadIdx.x;
  if (i >= n) return;
  int4 cc = coords[i];  // (b, x, y, z)
  uint32_t k = (((uint32_t)cc.x * 64u + ((uint32_t)cc.y >> 1)) * 64u
                + ((uint32_t)cc.z >> 1)) * 64u + ((uint32_t)cc.w >> 1);
  uint32_t r = atomicAdd(&cnt[k], 1u);   // arrival rank within group (small for this data)
  keys[i] = k | (r << 21);
}

// ---- pass 2a: per-block sums of (presence, count) --------------------------
__global__ void k_blocksum(const uint32_t* __restrict__ cnt,
                           uint32_t* __restrict__ blkP, uint32_t* __restrict__ blkM) {
  __shared__ uint32_t sp[SCAN_TPB], sm[SCAN_TPB];
  int t = threadIdx.x;
  int base = blockIdx.x * (SCAN_TPB * EPT) + t * EPT;
  const uint4* c4 = (const uint4*)(cnt + base);
  uint4 q0 = c4[0], q1 = c4[1];
  uint32_t p = (q0.x > 0) + (q0.y > 0) + (q0.z > 0) + (q0.w > 0)
             + (q1.x > 0) + (q1.y > 0) + (q1.z > 0) + (q1.w > 0);
  uint32_t m = q0.x + q0.y + q0.z + q0.w + q1.x + q1.y + q1.z + q1.w;
  sp[t] = p; sm[t] = m;
  __syncthreads();
  for (int off = SCAN_TPB / 2; off > 0; off >>= 1) {
    if (t < off) { sp[t] += sp[t + off]; sm[t] += sm[t + off]; }
    __syncthreads();
  }
  if (t == 0) { blkP[blockIdx.x] = sp[0]; blkM[blockIdx.x] = sm[0]; }
}

// ---- pass 2b: exclusive scan of 1024 block sums (single block) -------------
__global__ void k_scan_blksums(uint32_t* __restrict__ blkP, uint32_t* __restrict__ blkM,
                               uint32_t* __restrict__ totalK) {
  __shared__ uint32_t sp[SCAN_BLOCKS], sm[SCAN_BLOCKS];
  int t = threadIdx.x;
  sp[t] = blkP[t]; sm[t] = blkM[t];
  __syncthreads();
  for (int off = 1; off < SCAN_BLOCKS; off <<= 1) {
    uint32_t vp = (t >= off) ? sp[t - off] : 0u;
    uint32_t vm = (t >= off) ? sm[t - off] : 0u;
    __syncthreads();
    sp[t] += vp; sm[t] += vm;
    __syncthreads();
  }
  blkP[t] = t ? sp[t - 1] : 0u;   // exclusive
  blkM[t] = t ? sm[t - 1] : 0u;
  if (t == SCAN_BLOCKS - 1) *totalK = sp[SCAN_BLOCKS - 1];
}

// ---- pass 2c: finalize per-key rank/start; emit uniq keys + packed meta ----
__global__ void k_finalize(const uint32_t* __restrict__ cnt,
                           const uint32_t* __restrict__ blkP, const uint32_t* __restrict__ blkM,
                           uint32_t* __restrict__ cur,
                           uint64_t* __restrict__ denseMeta,
                           float* __restrict__ uniqOut) {
  __shared__ uint32_t sp[SCAN_TPB], sm[SCAN_TPB];
  int t = threadIdx.x;
  int base = blockIdx.x * (SCAN_TPB * EPT) + t * EPT;
  const uint4* c4 = (const uint4*)(cnt + base);
  uint4 q0 = c4[0], q1 = c4[1];
  uint32_t c[EPT] = {q0.x, q0.y, q0.z, q0.w, q1.x, q1.y, q1.z, q1.w};
  uint32_t p = 0, m = 0;
#pragma unroll
  for (int e = 0; e < EPT; e++) { p += (c[e] > 0); m += c[e]; }
  sp[t] = p; sm[t] = m;
  __syncthreads();
  for (int off = 1; off < SCAN_TPB; off <<= 1) {
    uint32_t vp = (t >= off) ? sp[t - off] : 0u;
    uint32_t vm = (t >= off) ? sm[t - off] : 0u;
    __syncthreads();
    sp[t] += vp; sm[t] += vm;
    __syncthreads();
  }
  uint32_t poff = blkP[blockIdx.x] + (t ? sp[t - 1] : 0u);
  uint32_t moff = blkM[blockIdx.x] + (t ? sm[t - 1] : 0u);
#pragma unroll
  for (int e = 0; e < EPT; e++) {
    if (c[e] > 0) {
      uint32_t k = (uint32_t)base + (uint32_t)e;
      cur[k] = moff;                               // group start (read-only downstream)
      denseMeta[poff] = ((uint64_t)c[e] << 32) | (uint64_t)moff;
      uniqOut[poff]   = (float)k;                  // sorted unique key, exact in f32
      poff++;
    }
    moff += c[e];
  }
}

// ---- pass 3: atomic-free counting-sort placement ----------------------------
__global__ void k_scatter(const uint32_t* __restrict__ keys, const uint32_t* __restrict__ cur,
                          uint32_t* __restrict__ sortedIdx, int n) {
  int i = blockIdx.x * blockDim.x + threadIdx.x;
  if (i >= n) return;
  uint32_t kk = keys[i];
  uint32_t pos = cur[kk & KMASK] + (kk >> 21);
  sortedIdx[pos] = (uint32_t)i;
}

// ---- pass 4: per-group mean; half-wave = 4 consecutive rows x 8 lanes x f4 --
__global__ __launch_bounds__(256, 8)
void k_pool(const float* __restrict__ feats, const uint32_t* __restrict__ sortedIdx,
            const uint64_t* __restrict__ denseMeta, const uint32_t* __restrict__ totalK,
            float* __restrict__ outFeats, float* __restrict__ uniqOut, int n) {
  const int tid = threadIdx.x;
  const int hw = tid >> 5;              // half-wave 0..7
  const int lane = tid & 31;
  const int subrow = lane >> 3;         // 0..3: which of 4 consecutive rows
  const int cl = lane & 7;              // float4 column within the 32-ch row
  const uint32_t K = *totalK;
  const int j = (blockIdx.x * 8 + hw) * 4 + subrow;
  const bool valid = j < n;
  const bool live = valid && ((uint32_t)j < K);

  uint32_t s_sub = 0, c_sub = 0;
  if (live) {
    uint64_t dm = denseMeta[j];         // 8 lanes same addr -> broadcast
    s_sub = (uint32_t)dm;
    c_sub = (uint32_t)(dm >> 32);
  }
  uint32_t midx = 0;                    // member cl of my row (up to 8 prefetched)
  if (live && (uint32_t)cl < c_sub) midx = sortedIdx[s_sub + (uint32_t)cl];

  vf4 acc = {0.f, 0.f, 0.f, 0.f};
  // slot 0: always useful for live rows (c >= 1)
  {
    uint32_t u = (uint32_t)__shfl((int)midx, subrow << 3, 32);
    vf4 v = *(const vf4*)(feats + (size_t)u * C + cl * 4);
    if (c_sub > 0u) acc += v;
  }
  // slots 1..7: wave-uniform early exit (avg group size ~1.7)
  for (uint32_t q = 1; q < 8u; ++q) {
    if (__all((int)(q >= c_sub))) break;
    uint32_t u = (uint32_t)__shfl((int)midx, (int)(((uint32_t)subrow << 3) | q), 32);
    vf4 v = *(const vf4*)(feats + (size_t)u * C + cl * 4);
    if (q < c_sub) acc += v;
  }
  // essentially-never fallback for c>8
  if (__any((int)(c_sub > 8u))) {
    for (uint32_t q = 8; q < c_sub; ++q) {
      uint32_t u = sortedIdx[s_sub + q];
      acc += *(const vf4*)(feats + (size_t)u * C + cl * 4);
    }
  }

  if (valid) {
    float invc = live ? 1.0f / (float)c_sub : 0.0f;
    vf4 o = acc * invc;
    __builtin_nontemporal_store(o, (vf4*)(outFeats + (size_t)j * C + cl * 4));
    if (!live && cl == 0) uniqOut[j] = -1.0f;   // folded-in uniq tail
  }
}

extern "C" void kernel_launch(void* const* d_in, const int* in_sizes, int n_in,
                              void* d_out, int out_size, void* d_ws, size_t ws_size,
                              hipStream_t stream) {
  const float* feats = (const float*)d_in[0];
  const int4* coords = (const int4*)d_in[1];
  int n = in_sizes[0] / C;   // N = 2,000,000

  char* ws = (char*)d_ws;
  const size_t MB = 1024u * 1024u;
  uint32_t* keys      = (uint32_t*)(ws + 0 * MB);    // n u32   (8 MB) key|rank<<21
  uint32_t* cnt       = (uint32_t*)(ws + 8 * MB);    // KS u32  (8 MB)
  uint32_t* cur       = (uint32_t*)(ws + 16 * MB);   // KS u32  (8 MB) group starts
  uint64_t* denseMeta = (uint64_t*)(ws + 24 * MB);   // <=n u64 (16 MB) {cnt,start}
  uint32_t* sortedIdx = (uint32_t*)(ws + 40 * MB);   // n u32   (8 MB)
  uint32_t* blkP      = (uint32_t*)(ws + 48 * MB);   // 1024 u32
  uint32_t* blkM      = blkP + SCAN_BLOCKS;          // 1024 u32
  uint32_t* totalK    = blkM + SCAN_BLOCKS;          // 1 u32

  float* outFeats = (float*)d_out;                   // [n, 32]
  float* uniqOut  = outFeats + (size_t)n * C;        // [n] keys as f32

  k_zero<<<KS / 4 / 256, 256, 0, stream>>>((uint4*)cnt, KS / 4);
  k_count<<<(n + 255) / 256, 256, 0, stream>>>(coords, keys, cnt, n);
  k_blocksum<<<SCAN_BLOCKS, SCAN_TPB, 0, stream>>>(cnt, blkP, blkM);
  k_scan_blksums<<<1, SCAN_BLOCKS, 0, stream>>>(blkP, blkM, totalK);
  k_finalize<<<SCAN_BLOCKS, SCAN_TPB, 0, stream>>>(cnt, blkP, blkM, cur, denseMeta, uniqOut);
  k_scatter<<<(n + 255) / 256, 256, 0, stream>>>(keys, cur, sortedIdx, n);
  k_pool<<<(n + 31) / 32, 256, 0, stream>>>(feats, sortedIdx, denseMeta, totalK, outFeats, uniqOut, n);
}

// Round 6
// 260.497 us; speedup vs baseline: 2.4022x; 1.0659x over previous
//
#include <hip/hip_runtime.h>
#include <stdint.h>

// Sparse 3D avg-pool, kernel=stride=2, GRID=128, B=8, C=32.
// Keyspace = 8*64^3 = 2^21 -> dense histogram + scan instead of sort/unique.
// Round 6: k_pool = 8 rows per half-wave (two quad-sets), 8 straight-line
// unconditional gathers in flight -> 2x memory-level parallelism.

#define KS (1u << 21)            // 2,097,152 possible keys
#define KMASK (KS - 1u)
#define SCAN_BLOCKS 1024
#define SCAN_TPB 256
#define EPT 8                    // elems per thread: 256*8=2048/block, *1024 = 2^21
#define C 32

typedef float vf4 __attribute__((ext_vector_type(4)));

// ---- pass 0: zero the histogram --------------------------------------------
__global__ void k_zero(uint4* __restrict__ p, int n4) {
  int i = blockIdx.x * blockDim.x + threadIdx.x;
  if (i < n4) p[i] = make_uint4(0u, 0u, 0u, 0u);
}

// ---- pass 1: key per voxel + dense histogram; rank packed in key bits ------
__global__ void k_count(const int4* __restrict__ coords, uint32_t* __restrict__ keys,
                        uint32_t* __restrict__ cnt, int n) {
  int i = blockIdx.x * blockDim.x + threadIdx.x;
  if (i >= n) return;
  int4 cc = coords[i];  // (b, x, y, z)
  uint32_t k = (((uint32_t)cc.x * 64u + ((uint32_t)cc.y >> 1)) * 64u
                + ((uint32_t)cc.z >> 1)) * 64u + ((uint32_t)cc.w >> 1);
  uint32_t r = atomicAdd(&cnt[k], 1u);   // arrival rank within group
  keys[i] = k | (r << 21);
}

// ---- pass 2a: per-block sums of (presence, count) --------------------------
__global__ void k_blocksum(const uint32_t* __restrict__ cnt,
                           uint32_t* __restrict__ blkP, uint32_t* __restrict__ blkM) {
  __shared__ uint32_t sp[SCAN_TPB], sm[SCAN_TPB];
  int t = threadIdx.x;
  int base = blockIdx.x * (SCAN_TPB * EPT) + t * EPT;
  const uint4* c4 = (const uint4*)(cnt + base);
  uint4 q0 = c4[0], q1 = c4[1];
  uint32_t p = (q0.x > 0) + (q0.y > 0) + (q0.z > 0) + (q0.w > 0)
             + (q1.x > 0) + (q1.y > 0) + (q1.z > 0) + (q1.w > 0);
  uint32_t m = q0.x + q0.y + q0.z + q0.w + q1.x + q1.y + q1.z + q1.w;
  sp[t] = p; sm[t] = m;
  __syncthreads();
  for (int off = SCAN_TPB / 2; off > 0; off >>= 1) {
    if (t < off) { sp[t] += sp[t + off]; sm[t] += sm[t + off]; }
    __syncthreads();
  }
  if (t == 0) { blkP[blockIdx.x] = sp[0]; blkM[blockIdx.x] = sm[0]; }
}

// ---- pass 2b: exclusive scan of 1024 block sums (single block) -------------
__global__ void k_scan_blksums(uint32_t* __restrict__ blkP, uint32_t* __restrict__ blkM,
                               uint32_t* __restrict__ totalK) {
  __shared__ uint32_t sp[SCAN_BLOCKS], sm[SCAN_BLOCKS];
  int t = threadIdx.x;
  sp[t] = blkP[t]; sm[t] = blkM[t];
  __syncthreads();
  for (int off = 1; off < SCAN_BLOCKS; off <<= 1) {
    uint32_t vp = (t >= off) ? sp[t - off] : 0u;
    uint32_t vm = (t >= off) ? sm[t - off] : 0u;
    __syncthreads();
    sp[t] += vp; sm[t] += vm;
    __syncthreads();
  }
  blkP[t] = t ? sp[t - 1] : 0u;   // exclusive
  blkM[t] = t ? sm[t - 1] : 0u;
  if (t == SCAN_BLOCKS - 1) *totalK = sp[SCAN_BLOCKS - 1];
}

// ---- pass 2c: finalize per-key rank/start; emit uniq keys + packed meta ----
__global__ void k_finalize(const uint32_t* __restrict__ cnt,
                           const uint32_t* __restrict__ blkP, const uint32_t* __restrict__ blkM,
                           uint32_t* __restrict__ cur,
                           uint64_t* __restrict__ denseMeta,
                           float* __restrict__ uniqOut) {
  __shared__ uint32_t sp[SCAN_TPB], sm[SCAN_TPB];
  int t = threadIdx.x;
  int base = blockIdx.x * (SCAN_TPB * EPT) + t * EPT;
  const uint4* c4 = (const uint4*)(cnt + base);
  uint4 q0 = c4[0], q1 = c4[1];
  uint32_t c[EPT] = {q0.x, q0.y, q0.z, q0.w, q1.x, q1.y, q1.z, q1.w};
  uint32_t p = 0, m = 0;
#pragma unroll
  for (int e = 0; e < EPT; e++) { p += (c[e] > 0); m += c[e]; }
  sp[t] = p; sm[t] = m;
  __syncthreads();
  for (int off = 1; off < SCAN_TPB; off <<= 1) {
    uint32_t vp = (t >= off) ? sp[t - off] : 0u;
    uint32_t vm = (t >= off) ? sm[t - off] : 0u;
    __syncthreads();
    sp[t] += vp; sm[t] += vm;
    __syncthreads();
  }
  uint32_t poff = blkP[blockIdx.x] + (t ? sp[t - 1] : 0u);
  uint32_t moff = blkM[blockIdx.x] + (t ? sm[t - 1] : 0u);
#pragma unroll
  for (int e = 0; e < EPT; e++) {
    if (c[e] > 0) {
      uint32_t k = (uint32_t)base + (uint32_t)e;
      cur[k] = moff;                               // group start
      denseMeta[poff] = ((uint64_t)c[e] << 32) | (uint64_t)moff;
      uniqOut[poff]   = (float)k;                  // exact in f32 (< 2^24)
      poff++;
    }
    moff += c[e];
  }
}

// ---- pass 3: atomic-free counting-sort placement ----------------------------
__global__ void k_scatter(const uint32_t* __restrict__ keys, const uint32_t* __restrict__ cur,
                          uint32_t* __restrict__ sortedIdx, int n) {
  int i = blockIdx.x * blockDim.x + threadIdx.x;
  if (i >= n) return;
  uint32_t kk = keys[i];
  uint32_t pos = cur[kk & KMASK] + (kk >> 21);
  sortedIdx[pos] = (uint32_t)i;
}

// ---- pass 4: per-group mean; half-wave = 8 rows (two quad-sets A/B) --------
__global__ __launch_bounds__(256, 8)
void k_pool(const float* __restrict__ feats, const uint32_t* __restrict__ sortedIdx,
            const uint64_t* __restrict__ denseMeta, const uint32_t* __restrict__ totalK,
            float* __restrict__ outFeats, float* __restrict__ uniqOut, int n) {
  const int tid = threadIdx.x;
  const int hw = tid >> 5;              // half-wave 0..7
  const int lane = tid & 31;
  const int subrow = lane >> 3;         // 0..3
  const int cl = lane & 7;              // float4 column
  const uint32_t K = *totalK;
  const int j0 = (blockIdx.x * 8 + hw) * 8;     // 8 consecutive rows
  const int jA = j0 + subrow;
  const int jB = j0 + 4 + subrow;

  const bool vA = jA < n, vB = jB < n;
  const bool lA = vA && (uint32_t)jA < K;
  const bool lB = vB && (uint32_t)jB < K;

  uint32_t sA = 0, cA = 0, sB = 0, cB = 0;
  if (lA) { uint64_t dm = denseMeta[jA]; sA = (uint32_t)dm; cA = (uint32_t)(dm >> 32); }
  if (lB) { uint64_t dm = denseMeta[jB]; sB = (uint32_t)dm; cB = (uint32_t)(dm >> 32); }

  uint32_t iA = 0, iB = 0;              // member cl of my row (up to 8 prefetched)
  if (lA && (uint32_t)cl < cA) iA = sortedIdx[sA + (uint32_t)cl];
  if (lB && (uint32_t)cl < cB) iB = sortedIdx[sB + (uint32_t)cl];

  vf4 aA = {0.f, 0.f, 0.f, 0.f}, aB = {0.f, 0.f, 0.f, 0.f};
  // 8 straight-line gathers, no branches between loads -> all in flight.
#pragma unroll
  for (int q = 0; q < 4; ++q) {
    uint32_t uA = (uint32_t)__shfl((int)iA, (subrow << 3) | q, 32);
    uint32_t uB = (uint32_t)__shfl((int)iB, (subrow << 3) | q, 32);
    vf4 xA = *(const vf4*)(feats + (size_t)uA * C + cl * 4);
    vf4 xB = *(const vf4*)(feats + (size_t)uB * C + cl * 4);
    aA += ((uint32_t)q < cA) ? xA : (vf4){0.f, 0.f, 0.f, 0.f};
    aB += ((uint32_t)q < cB) ? xB : (vf4){0.f, 0.f, 0.f, 0.f};
  }
  // tail to c<=8 (~0.5% of rows): union vote across both sets
  for (uint32_t q = 4; q < 8u; ++q) {
    if (__all((int)(q >= cA && q >= cB))) break;
    uint32_t uA = (uint32_t)__shfl((int)iA, (int)(((uint32_t)subrow << 3) | q), 32);
    uint32_t uB = (uint32_t)__shfl((int)iB, (int)(((uint32_t)subrow << 3) | q), 32);
    if (q < cA) aA += *(const vf4*)(feats + (size_t)uA * C + cl * 4);
    if (q < cB) aB += *(const vf4*)(feats + (size_t)uB * C + cl * 4);
  }
  // essentially-never fallback for c>8
  if (__any((int)(cA > 8u || cB > 8u))) {
    for (uint32_t q = 8; q < cA; ++q)
      aA += *(const vf4*)(feats + (size_t)sortedIdx[sA + q] * C + cl * 4);
    for (uint32_t q = 8; q < cB; ++q)
      aB += *(const vf4*)(feats + (size_t)sortedIdx[sB + q] * C + cl * 4);
  }

  if (vA) {
    float inv = lA ? 1.0f / (float)cA : 0.0f;
    vf4 o = aA * inv;
    __builtin_nontemporal_store(o, (vf4*)(outFeats + (size_t)jA * C + cl * 4));
    if (!lA && cl == 0) uniqOut[jA] = -1.0f;
  }
  if (vB) {
    float inv = lB ? 1.0f / (float)cB : 0.0f;
    vf4 o = aB * inv;
    __builtin_nontemporal_store(o, (vf4*)(outFeats + (size_t)jB * C + cl * 4));
    if (!lB && cl == 0) uniqOut[jB] = -1.0f;
  }
}

extern "C" void kernel_launch(void* const* d_in, const int* in_sizes, int n_in,
                              void* d_out, int out_size, void* d_ws, size_t ws_size,
                              hipStream_t stream) {
  const float* feats = (const float*)d_in[0];
  const int4* coords = (const int4*)d_in[1];
  int n = in_sizes[0] / C;   // N = 2,000,000

  char* ws = (char*)d_ws;
  const size_t MB = 1024u * 1024u;
  uint32_t* keys      = (uint32_t*)(ws + 0 * MB);    // n u32   (8 MB) key|rank<<21
  uint32_t* cnt       = (uint32_t*)(ws + 8 * MB);    // KS u32  (8 MB)
  uint32_t* cur       = (uint32_t*)(ws + 16 * MB);   // KS u32  (8 MB) group starts
  uint64_t* denseMeta = (uint64_t*)(ws + 24 * MB);   // <=n u64 (16 MB) {cnt,start}
  uint32_t* sortedIdx = (uint32_t*)(ws + 40 * MB);   // n u32   (8 MB)
  uint32_t* blkP      = (uint32_t*)(ws + 48 * MB);   // 1024 u32
  uint32_t* blkM      = blkP + SCAN_BLOCKS;          // 1024 u32
  uint32_t* totalK    = blkM + SCAN_BLOCKS;          // 1 u32

  float* outFeats = (float*)d_out;                   // [n, 32]
  float* uniqOut  = outFeats + (size_t)n * C;        // [n] keys as f32

  k_zero<<<KS / 4 / 256, 256, 0, stream>>>((uint4*)cnt, KS / 4);
  k_count<<<(n + 255) / 256, 256, 0, stream>>>(coords, keys, cnt, n);
  k_blocksum<<<SCAN_BLOCKS, SCAN_TPB, 0, stream>>>(cnt, blkP, blkM);
  k_scan_blksums<<<1, SCAN_BLOCKS, 0, stream>>>(blkP, blkM, totalK);
  k_finalize<<<SCAN_BLOCKS, SCAN_TPB, 0, stream>>>(cnt, blkP, blkM, cur, denseMeta, uniqOut);
  k_scatter<<<(n + 255) / 256, 256, 0, stream>>>(keys, cur, sortedIdx, n);
  k_pool<<<(n + 63) / 64, 256, 0, stream>>>(feats, sortedIdx, denseMeta, totalK, outFeats, uniqOut, n);
}

// Round 7
// 258.606 us; speedup vs baseline: 2.4198x; 1.0073x over previous
//
#include <hip/hip_runtime.h>
#include <stdint.h>

// Sparse 3D avg-pool, kernel=stride=2, GRID=128, B=8, C=32.
// Keyspace = 8*64^3 = 2^21 -> dense histogram + scan instead of sort/unique.
// Round 7: 4x-unrolled k_count/k_scatter (4 atomics/gathers in flight per
// thread), scan folded into k_finalize (per-block reduction of partials).

#define KS (1u << 21)            // 2,097,152 possible keys
#define KMASK (KS - 1u)
#define SCAN_BLOCKS 1024
#define SCAN_TPB 256
#define EPT 8                    // elems per thread: 256*8=2048/block, *1024 = 2^21
#define C 32
#define UNROLL 4

typedef float vf4 __attribute__((ext_vector_type(4)));

// ---- pass 0: zero the histogram --------------------------------------------
__global__ void k_zero(uint4* __restrict__ p, int n4) {
  int i = blockIdx.x * blockDim.x + threadIdx.x;
  if (i < n4) p[i] = make_uint4(0u, 0u, 0u, 0u);
}

// ---- pass 1: key per voxel + dense histogram; rank packed in key bits ------
// 4 elements/thread -> 4 independent atomic round trips in flight.
__global__ void k_count(const int4* __restrict__ coords, uint32_t* __restrict__ keys,
                        uint32_t* __restrict__ cnt, int n) {
  int base = blockIdx.x * (256 * UNROLL) + threadIdx.x;
  int4 cc[UNROLL];
  uint32_t k[UNROLL];
#pragma unroll
  for (int u = 0; u < UNROLL; ++u) {
    int i = base + u * 256;
    if (i < n) cc[u] = coords[i];
  }
#pragma unroll
  for (int u = 0; u < UNROLL; ++u) {
    int i = base + u * 256;
    if (i < n) {
      k[u] = (((uint32_t)cc[u].x * 64u + ((uint32_t)cc[u].y >> 1)) * 64u
              + ((uint32_t)cc[u].z >> 1)) * 64u + ((uint32_t)cc[u].w >> 1);
      uint32_t r = atomicAdd(&cnt[k[u]], 1u);
      keys[i] = k[u] | (r << 21);
    }
  }
}

// ---- pass 2a: per-block sums of (presence, count) --------------------------
__global__ void k_blocksum(const uint32_t* __restrict__ cnt,
                           uint32_t* __restrict__ blkP, uint32_t* __restrict__ blkM) {
  __shared__ uint32_t sp[SCAN_TPB], sm[SCAN_TPB];
  int t = threadIdx.x;
  int base = blockIdx.x * (SCAN_TPB * EPT) + t * EPT;
  const uint4* c4 = (const uint4*)(cnt + base);
  uint4 q0 = c4[0], q1 = c4[1];
  uint32_t p = (q0.x > 0) + (q0.y > 0) + (q0.z > 0) + (q0.w > 0)
             + (q1.x > 0) + (q1.y > 0) + (q1.z > 0) + (q1.w > 0);
  uint32_t m = q0.x + q0.y + q0.z + q0.w + q1.x + q1.y + q1.z + q1.w;
  sp[t] = p; sm[t] = m;
  __syncthreads();
  for (int off = SCAN_TPB / 2; off > 0; off >>= 1) {
    if (t < off) { sp[t] += sp[t + off]; sm[t] += sm[t + off]; }
    __syncthreads();
  }
  if (t == 0) { blkP[blockIdx.x] = sp[0]; blkM[blockIdx.x] = sm[0]; }
}

// ---- pass 2b: finalize (scan folded in: per-block reduction of partials) ---
__global__ void k_finalize(const uint32_t* __restrict__ cnt,
                           const uint32_t* __restrict__ blkP, const uint32_t* __restrict__ blkM,
                           uint32_t* __restrict__ cur,
                           uint64_t* __restrict__ denseMeta,
                           float* __restrict__ uniqOut,
                           uint32_t* __restrict__ totalK) {
  __shared__ uint64_t rAll[SCAN_TPB], rBel[SCAN_TPB];
  __shared__ uint32_t sp[SCAN_TPB], sm[SCAN_TPB];
  const int t = threadIdx.x;
  const int b = blockIdx.x;

  // reduce 1024 partials: full sum + prefix-below-b, packed (p<<32)|m
  uint64_t all = 0, bel = 0;
  for (int u = t; u < SCAN_BLOCKS; u += SCAN_TPB) {
    uint64_t v = ((uint64_t)blkP[u] << 32) | (uint64_t)blkM[u];
    all += v;
    if (u < b) bel += v;
  }
  rAll[t] = all; rBel[t] = bel;
  __syncthreads();
  for (int off = SCAN_TPB / 2; off > 0; off >>= 1) {
    if (t < off) { rAll[t] += rAll[t + off]; rBel[t] += rBel[t + off]; }
    __syncthreads();
  }
  const uint32_t blockP = (uint32_t)(rBel[0] >> 32);
  const uint32_t blockM = (uint32_t)rBel[0];
  if (b == 0 && t == 0) *totalK = (uint32_t)(rAll[0] >> 32);

  // intra-block scan over this block's 2048 histogram cells
  int base = b * (SCAN_TPB * EPT) + t * EPT;
  const uint4* c4 = (const uint4*)(cnt + base);
  uint4 q0 = c4[0], q1 = c4[1];
  uint32_t c[EPT] = {q0.x, q0.y, q0.z, q0.w, q1.x, q1.y, q1.z, q1.w};
  uint32_t p = 0, m = 0;
#pragma unroll
  for (int e = 0; e < EPT; e++) { p += (c[e] > 0); m += c[e]; }
  sp[t] = p; sm[t] = m;
  __syncthreads();
  for (int off = 1; off < SCAN_TPB; off <<= 1) {
    uint32_t vp = (t >= off) ? sp[t - off] : 0u;
    uint32_t vm = (t >= off) ? sm[t - off] : 0u;
    __syncthreads();
    sp[t] += vp; sm[t] += vm;
    __syncthreads();
  }
  uint32_t poff = blockP + (t ? sp[t - 1] : 0u);
  uint32_t moff = blockM + (t ? sm[t - 1] : 0u);
#pragma unroll
  for (int e = 0; e < EPT; e++) {
    if (c[e] > 0) {
      uint32_t k = (uint32_t)base + (uint32_t)e;
      cur[k] = moff;                               // group start
      denseMeta[poff] = ((uint64_t)c[e] << 32) | (uint64_t)moff;
      uniqOut[poff]   = (float)k;                  // exact in f32 (< 2^24)
      poff++;
    }
    moff += c[e];
  }
}

// ---- pass 3: atomic-free counting-sort placement, 4x unrolled ---------------
__global__ void k_scatter(const uint32_t* __restrict__ keys, const uint32_t* __restrict__ cur,
                          uint32_t* __restrict__ sortedIdx, int n) {
  int base = blockIdx.x * (256 * UNROLL) + threadIdx.x;
  uint32_t kk[UNROLL];
#pragma unroll
  for (int u = 0; u < UNROLL; ++u) {
    int i = base + u * 256;
    if (i < n) kk[u] = keys[i];
  }
#pragma unroll
  for (int u = 0; u < UNROLL; ++u) {
    int i = base + u * 256;
    if (i < n) {
      uint32_t pos = cur[kk[u] & KMASK] + (kk[u] >> 21);
      sortedIdx[pos] = (uint32_t)i;
    }
  }
}

// ---- pass 4: per-group mean; half-wave = 8 rows (two quad-sets A/B) --------
__global__ __launch_bounds__(256, 8)
void k_pool(const float* __restrict__ feats, const uint32_t* __restrict__ sortedIdx,
            const uint64_t* __restrict__ denseMeta, const uint32_t* __restrict__ totalK,
            float* __restrict__ outFeats, float* __restrict__ uniqOut, int n) {
  const int tid = threadIdx.x;
  const int hw = tid >> 5;              // half-wave 0..7
  const int lane = tid & 31;
  const int subrow = lane >> 3;         // 0..3
  const int cl = lane & 7;              // float4 column
  const uint32_t K = *totalK;
  const int j0 = (blockIdx.x * 8 + hw) * 8;     // 8 consecutive rows
  const int jA = j0 + subrow;
  const int jB = j0 + 4 + subrow;

  const bool vA = jA < n, vB = jB < n;
  const bool lA = vA && (uint32_t)jA < K;
  const bool lB = vB && (uint32_t)jB < K;

  uint32_t sA = 0, cA = 0, sB = 0, cB = 0;
  if (lA) { uint64_t dm = denseMeta[jA]; sA = (uint32_t)dm; cA = (uint32_t)(dm >> 32); }
  if (lB) { uint64_t dm = denseMeta[jB]; sB = (uint32_t)dm; cB = (uint32_t)(dm >> 32); }

  uint32_t iA = 0, iB = 0;              // member cl of my row (up to 8 prefetched)
  if (lA && (uint32_t)cl < cA) iA = sortedIdx[sA + (uint32_t)cl];
  if (lB && (uint32_t)cl < cB) iB = sortedIdx[sB + (uint32_t)cl];

  vf4 aA = {0.f, 0.f, 0.f, 0.f}, aB = {0.f, 0.f, 0.f, 0.f};
  // 8 straight-line gathers, no branches between loads -> all in flight.
#pragma unroll
  for (int q = 0; q < 4; ++q) {
    uint32_t uA = (uint32_t)__shfl((int)iA, (subrow << 3) | q, 32);
    uint32_t uB = (uint32_t)__shfl((int)iB, (subrow << 3) | q, 32);
    vf4 xA = *(const vf4*)(feats + (size_t)uA * C + cl * 4);
    vf4 xB = *(const vf4*)(feats + (size_t)uB * C + cl * 4);
    aA += ((uint32_t)q < cA) ? xA : (vf4){0.f, 0.f, 0.f, 0.f};
    aB += ((uint32_t)q < cB) ? xB : (vf4){0.f, 0.f, 0.f, 0.f};
  }
  // tail to c<=8 (~0.5% of rows): union vote across both sets
  for (uint32_t q = 4; q < 8u; ++q) {
    if (__all((int)(q >= cA && q >= cB))) break;
    uint32_t uA = (uint32_t)__shfl((int)iA, (int)(((uint32_t)subrow << 3) | q), 32);
    uint32_t uB = (uint32_t)__shfl((int)iB, (int)(((uint32_t)subrow << 3) | q), 32);
    if (q < cA) aA += *(const vf4*)(feats + (size_t)uA * C + cl * 4);
    if (q < cB) aB += *(const vf4*)(feats + (size_t)uB * C + cl * 4);
  }
  // essentially-never fallback for c>8
  if (__any((int)(cA > 8u || cB > 8u))) {
    for (uint32_t q = 8; q < cA; ++q)
      aA += *(const vf4*)(feats + (size_t)sortedIdx[sA + q] * C + cl * 4);
    for (uint32_t q = 8; q < cB; ++q)
      aB += *(const vf4*)(feats + (size_t)sortedIdx[sB + q] * C + cl * 4);
  }

  if (vA) {
    float inv = lA ? 1.0f / (float)cA : 0.0f;
    vf4 o = aA * inv;
    __builtin_nontemporal_store(o, (vf4*)(outFeats + (size_t)jA * C + cl * 4));
    if (!lA && cl == 0) uniqOut[jA] = -1.0f;
  }
  if (vB) {
    float inv = lB ? 1.0f / (float)cB : 0.0f;
    vf4 o = aB * inv;
    __builtin_nontemporal_store(o, (vf4*)(outFeats + (size_t)jB * C + cl * 4));
    if (!lB && cl == 0) uniqOut[jB] = -1.0f;
  }
}

extern "C" void kernel_launch(void* const* d_in, const int* in_sizes, int n_in,
                              void* d_out, int out_size, void* d_ws, size_t ws_size,
                              hipStream_t stream) {
  const float* feats = (const float*)d_in[0];
  const int4* coords = (const int4*)d_in[1];
  int n = in_sizes[0] / C;   // N = 2,000,000

  char* ws = (char*)d_ws;
  const size_t MB = 1024u * 1024u;
  uint32_t* keys      = (uint32_t*)(ws + 0 * MB);    // n u32   (8 MB) key|rank<<21
  uint32_t* cnt       = (uint32_t*)(ws + 8 * MB);    // KS u32  (8 MB)
  uint32_t* cur       = (uint32_t*)(ws + 16 * MB);   // KS u32  (8 MB) group starts
  uint64_t* denseMeta = (uint64_t*)(ws + 24 * MB);   // <=n u64 (16 MB) {cnt,start}
  uint32_t* sortedIdx = (uint32_t*)(ws + 40 * MB);   // n u32   (8 MB)
  uint32_t* blkP      = (uint32_t*)(ws + 48 * MB);   // 1024 u32
  uint32_t* blkM      = blkP + SCAN_BLOCKS;          // 1024 u32
  uint32_t* totalK    = blkM + SCAN_BLOCKS;          // 1 u32

  float* outFeats = (float*)d_out;                   // [n, 32]
  float* uniqOut  = outFeats + (size_t)n * C;        // [n] keys as f32

  int chunk = 256 * UNROLL;
  k_zero<<<KS / 4 / 256, 256, 0, stream>>>((uint4*)cnt, KS / 4);
  k_count<<<(n + chunk - 1) / chunk, 256, 0, stream>>>(coords, keys, cnt, n);
  k_blocksum<<<SCAN_BLOCKS, SCAN_TPB, 0, stream>>>(cnt, blkP, blkM);
  k_finalize<<<SCAN_BLOCKS, SCAN_TPB, 0, stream>>>(cnt, blkP, blkM, cur, denseMeta, uniqOut, totalK);
  k_scatter<<<(n + chunk - 1) / chunk, 256, 0, stream>>>(keys, cur, sortedIdx, n);
  k_pool<<<(n + 63) / 64, 256, 0, stream>>>(feats, sortedIdx, denseMeta, totalK, outFeats, uniqOut, n);
}

// Round 8
// 254.887 us; speedup vs baseline: 2.4551x; 1.0146x over previous
//
#include <hip/hip_runtime.h>
#include <stdint.h>

// Sparse 3D avg-pool, kernel=stride=2, GRID=128, B=8, C=32.
// Keyspace = 8*64^3 = 2^21 -> dense histogram + scan instead of sort/unique.
// Round 8: phase-split k_count/k_scatter — issue ALL 8 atomics (resp. gathers)
// back-to-back before any dependent store, so 8 L3 round trips overlap.

#define KS (1u << 21)            // 2,097,152 possible keys
#define KMASK (KS - 1u)
#define SCAN_BLOCKS 1024
#define SCAN_TPB 256
#define EPT 8                    // elems per thread: 256*8=2048/block, *1024 = 2^21
#define C 32
#define UNROLL 8

typedef float vf4 __attribute__((ext_vector_type(4)));

// ---- pass 0: zero the histogram --------------------------------------------
__global__ void k_zero(uint4* __restrict__ p, int n4) {
  int i = blockIdx.x * blockDim.x + threadIdx.x;
  if (i < n4) p[i] = make_uint4(0u, 0u, 0u, 0u);
}

// ---- pass 1: key per voxel + dense histogram; rank packed in key bits ------
// Phase-split: 8 loads | 8 atomics issued back-to-back | 8 stores.
__global__ void k_count(const int4* __restrict__ coords, uint32_t* __restrict__ keys,
                        uint32_t* __restrict__ cnt, int n) {
  const int base = blockIdx.x * (256 * UNROLL) + threadIdx.x;
  const bool full = (blockIdx.x + 1) * (256 * UNROLL) <= n;
  if (full) {
    int4 cc[UNROLL];
    uint32_t k[UNROLL], r[UNROLL];
#pragma unroll
    for (int u = 0; u < UNROLL; ++u) cc[u] = coords[base + u * 256];
#pragma unroll
    for (int u = 0; u < UNROLL; ++u)
      k[u] = (((uint32_t)cc[u].x * 64u + ((uint32_t)cc[u].y >> 1)) * 64u
              + ((uint32_t)cc[u].z >> 1)) * 64u + ((uint32_t)cc[u].w >> 1);
#pragma unroll
    for (int u = 0; u < UNROLL; ++u) r[u] = atomicAdd(&cnt[k[u]], 1u);
#pragma unroll
    for (int u = 0; u < UNROLL; ++u) keys[base + u * 256] = k[u] | (r[u] << 21);
  } else {
    for (int u = 0; u < UNROLL; ++u) {
      int i = base + u * 256;
      if (i < n) {
        int4 cc = coords[i];
        uint32_t k = (((uint32_t)cc.x * 64u + ((uint32_t)cc.y >> 1)) * 64u
                      + ((uint32_t)cc.z >> 1)) * 64u + ((uint32_t)cc.w >> 1);
        uint32_t r = atomicAdd(&cnt[k], 1u);
        keys[i] = k | (r << 21);
      }
    }
  }
}

// ---- pass 2a: per-block sums of (presence, count) --------------------------
__global__ void k_blocksum(const uint32_t* __restrict__ cnt,
                           uint32_t* __restrict__ blkP, uint32_t* __restrict__ blkM) {
  __shared__ uint32_t sp[SCAN_TPB], sm[SCAN_TPB];
  int t = threadIdx.x;
  int base = blockIdx.x * (SCAN_TPB * EPT) + t * EPT;
  const uint4* c4 = (const uint4*)(cnt + base);
  uint4 q0 = c4[0], q1 = c4[1];
  uint32_t p = (q0.x > 0) + (q0.y > 0) + (q0.z > 0) + (q0.w > 0)
             + (q1.x > 0) + (q1.y > 0) + (q1.z > 0) + (q1.w > 0);
  uint32_t m = q0.x + q0.y + q0.z + q0.w + q1.x + q1.y + q1.z + q1.w;
  sp[t] = p; sm[t] = m;
  __syncthreads();
  for (int off = SCAN_TPB / 2; off > 0; off >>= 1) {
    if (t < off) { sp[t] += sp[t + off]; sm[t] += sm[t + off]; }
    __syncthreads();
  }
  if (t == 0) { blkP[blockIdx.x] = sp[0]; blkM[blockIdx.x] = sm[0]; }
}

// ---- pass 2b: finalize (scan folded in: per-block reduction of partials) ---
__global__ void k_finalize(const uint32_t* __restrict__ cnt,
                           const uint32_t* __restrict__ blkP, const uint32_t* __restrict__ blkM,
                           uint32_t* __restrict__ cur,
                           uint64_t* __restrict__ denseMeta,
                           float* __restrict__ uniqOut,
                           uint32_t* __restrict__ totalK) {
  __shared__ uint64_t rAll[SCAN_TPB], rBel[SCAN_TPB];
  __shared__ uint32_t sp[SCAN_TPB], sm[SCAN_TPB];
  const int t = threadIdx.x;
  const int b = blockIdx.x;

  // reduce 1024 partials: full sum + prefix-below-b, packed (p<<32)|m
  uint64_t all = 0, bel = 0;
  for (int u = t; u < SCAN_BLOCKS; u += SCAN_TPB) {
    uint64_t v = ((uint64_t)blkP[u] << 32) | (uint64_t)blkM[u];
    all += v;
    if (u < b) bel += v;
  }
  rAll[t] = all; rBel[t] = bel;
  __syncthreads();
  for (int off = SCAN_TPB / 2; off > 0; off >>= 1) {
    if (t < off) { rAll[t] += rAll[t + off]; rBel[t] += rBel[t + off]; }
    __syncthreads();
  }
  const uint32_t blockP = (uint32_t)(rBel[0] >> 32);
  const uint32_t blockM = (uint32_t)rBel[0];
  if (b == 0 && t == 0) *totalK = (uint32_t)(rAll[0] >> 32);

  // intra-block scan over this block's 2048 histogram cells
  int base = b * (SCAN_TPB * EPT) + t * EPT;
  const uint4* c4 = (const uint4*)(cnt + base);
  uint4 q0 = c4[0], q1 = c4[1];
  uint32_t c[EPT] = {q0.x, q0.y, q0.z, q0.w, q1.x, q1.y, q1.z, q1.w};
  uint32_t p = 0, m = 0;
#pragma unroll
  for (int e = 0; e < EPT; e++) { p += (c[e] > 0); m += c[e]; }
  sp[t] = p; sm[t] = m;
  __syncthreads();
  for (int off = 1; off < SCAN_TPB; off <<= 1) {
    uint32_t vp = (t >= off) ? sp[t - off] : 0u;
    uint32_t vm = (t >= off) ? sm[t - off] : 0u;
    __syncthreads();
    sp[t] += vp; sm[t] += vm;
    __syncthreads();
  }
  uint32_t poff = blockP + (t ? sp[t - 1] : 0u);
  uint32_t moff = blockM + (t ? sm[t - 1] : 0u);
#pragma unroll
  for (int e = 0; e < EPT; e++) {
    if (c[e] > 0) {
      uint32_t k = (uint32_t)base + (uint32_t)e;
      cur[k] = moff;                               // group start
      denseMeta[poff] = ((uint64_t)c[e] << 32) | (uint64_t)moff;
      uniqOut[poff]   = (float)k;                  // exact in f32 (< 2^24)
      poff++;
    }
    moff += c[e];
  }
}

// ---- pass 3: atomic-free counting-sort placement, phase-split ---------------
__global__ void k_scatter(const uint32_t* __restrict__ keys, const uint32_t* __restrict__ cur,
                          uint32_t* __restrict__ sortedIdx, int n) {
  const int base = blockIdx.x * (256 * UNROLL) + threadIdx.x;
  const bool full = (blockIdx.x + 1) * (256 * UNROLL) <= n;
  if (full) {
    uint32_t kk[UNROLL], st[UNROLL];
#pragma unroll
    for (int u = 0; u < UNROLL; ++u) kk[u] = keys[base + u * 256];
#pragma unroll
    for (int u = 0; u < UNROLL; ++u) st[u] = cur[kk[u] & KMASK];
#pragma unroll
    for (int u = 0; u < UNROLL; ++u)
      sortedIdx[st[u] + (kk[u] >> 21)] = (uint32_t)(base + u * 256);
  } else {
    for (int u = 0; u < UNROLL; ++u) {
      int i = base + u * 256;
      if (i < n) {
        uint32_t kk = keys[i];
        sortedIdx[cur[kk & KMASK] + (kk >> 21)] = (uint32_t)i;
      }
    }
  }
}

// ---- pass 4: per-group mean; half-wave = 8 rows (two quad-sets A/B) --------
__global__ __launch_bounds__(256, 8)
void k_pool(const float* __restrict__ feats, const uint32_t* __restrict__ sortedIdx,
            const uint64_t* __restrict__ denseMeta, const uint32_t* __restrict__ totalK,
            float* __restrict__ outFeats, float* __restrict__ uniqOut, int n) {
  const int tid = threadIdx.x;
  const int hw = tid >> 5;              // half-wave 0..7
  const int lane = tid & 31;
  const int subrow = lane >> 3;         // 0..3
  const int cl = lane & 7;              // float4 column
  const uint32_t K = *totalK;
  const int j0 = (blockIdx.x * 8 + hw) * 8;     // 8 consecutive rows
  const int jA = j0 + subrow;
  const int jB = j0 + 4 + subrow;

  const bool vA = jA < n, vB = jB < n;
  const bool lA = vA && (uint32_t)jA < K;
  const bool lB = vB && (uint32_t)jB < K;

  uint32_t sA = 0, cA = 0, sB = 0, cB = 0;
  if (lA) { uint64_t dm = denseMeta[jA]; sA = (uint32_t)dm; cA = (uint32_t)(dm >> 32); }
  if (lB) { uint64_t dm = denseMeta[jB]; sB = (uint32_t)dm; cB = (uint32_t)(dm >> 32); }

  uint32_t iA = 0, iB = 0;              // member cl of my row (up to 8 prefetched)
  if (lA && (uint32_t)cl < cA) iA = sortedIdx[sA + (uint32_t)cl];
  if (lB && (uint32_t)cl < cB) iB = sortedIdx[sB + (uint32_t)cl];

  vf4 aA = {0.f, 0.f, 0.f, 0.f}, aB = {0.f, 0.f, 0.f, 0.f};
  // 8 straight-line gathers, no branches between loads -> all in flight.
#pragma unroll
  for (int q = 0; q < 4; ++q) {
    uint32_t uA = (uint32_t)__shfl((int)iA, (subrow << 3) | q, 32);
    uint32_t uB = (uint32_t)__shfl((int)iB, (subrow << 3) | q, 32);
    vf4 xA = *(const vf4*)(feats + (size_t)uA * C + cl * 4);
    vf4 xB = *(const vf4*)(feats + (size_t)uB * C + cl * 4);
    aA += ((uint32_t)q < cA) ? xA : (vf4){0.f, 0.f, 0.f, 0.f};
    aB += ((uint32_t)q < cB) ? xB : (vf4){0.f, 0.f, 0.f, 0.f};
  }
  // tail to c<=8 (~0.5% of rows): union vote across both sets
  for (uint32_t q = 4; q < 8u; ++q) {
    if (__all((int)(q >= cA && q >= cB))) break;
    uint32_t uA = (uint32_t)__shfl((int)iA, (int)(((uint32_t)subrow << 3) | q), 32);
    uint32_t uB = (uint32_t)__shfl((int)iB, (int)(((uint32_t)subrow << 3) | q), 32);
    if (q < cA) aA += *(const vf4*)(feats + (size_t)uA * C + cl * 4);
    if (q < cB) aB += *(const vf4*)(feats + (size_t)uB * C + cl * 4);
  }
  // essentially-never fallback for c>8
  if (__any((int)(cA > 8u || cB > 8u))) {
    for (uint32_t q = 8; q < cA; ++q)
      aA += *(const vf4*)(feats + (size_t)sortedIdx[sA + q] * C + cl * 4);
    for (uint32_t q = 8; q < cB; ++q)
      aB += *(const vf4*)(feats + (size_t)sortedIdx[sB + q] * C + cl * 4);
  }

  if (vA) {
    float inv = lA ? 1.0f / (float)cA : 0.0f;
    vf4 o = aA * inv;
    __builtin_nontemporal_store(o, (vf4*)(outFeats + (size_t)jA * C + cl * 4));
    if (!lA && cl == 0) uniqOut[jA] = -1.0f;
  }
  if (vB) {
    float inv = lB ? 1.0f / (float)cB : 0.0f;
    vf4 o = aB * inv;
    __builtin_nontemporal_store(o, (vf4*)(outFeats + (size_t)jB * C + cl * 4));
    if (!lB && cl == 0) uniqOut[jB] = -1.0f;
  }
}

extern "C" void kernel_launch(void* const* d_in, const int* in_sizes, int n_in,
                              void* d_out, int out_size, void* d_ws, size_t ws_size,
                              hipStream_t stream) {
  const float* feats = (const float*)d_in[0];
  const int4* coords = (const int4*)d_in[1];
  int n = in_sizes[0] / C;   // N = 2,000,000

  char* ws = (char*)d_ws;
  const size_t MB = 1024u * 1024u;
  uint32_t* keys      = (uint32_t*)(ws + 0 * MB);    // n u32   (8 MB) key|rank<<21
  uint32_t* cnt       = (uint32_t*)(ws + 8 * MB);    // KS u32  (8 MB)
  uint32_t* cur       = (uint32_t*)(ws + 16 * MB);   // KS u32  (8 MB) group starts
  uint64_t* denseMeta = (uint64_t*)(ws + 24 * MB);   // <=n u64 (16 MB) {cnt,start}
  uint32_t* sortedIdx = (uint32_t*)(ws + 40 * MB);   // n u32   (8 MB)
  uint32_t* blkP      = (uint32_t*)(ws + 48 * MB);   // 1024 u32
  uint32_t* blkM      = blkP + SCAN_BLOCKS;          // 1024 u32
  uint32_t* totalK    = blkM + SCAN_BLOCKS;          // 1 u32

  float* outFeats = (float*)d_out;                   // [n, 32]
  float* uniqOut  = outFeats + (size_t)n * C;        // [n] keys as f32

  int chunk = 256 * UNROLL;
  k_zero<<<KS / 4 / 256, 256, 0, stream>>>((uint4*)cnt, KS / 4);
  k_count<<<(n + chunk - 1) / chunk, 256, 0, stream>>>(coords, keys, cnt, n);
  k_blocksum<<<SCAN_BLOCKS, SCAN_TPB, 0, stream>>>(cnt, blkP, blkM);
  k_finalize<<<SCAN_BLOCKS, SCAN_TPB, 0, stream>>>(cnt, blkP, blkM, cur, denseMeta, uniqOut, totalK);
  k_scatter<<<(n + chunk - 1) / chunk, 256, 0, stream>>>(keys, cur, sortedIdx, n);
  k_pool<<<(n + 63) / 64, 256, 0, stream>>>(feats, sortedIdx, denseMeta, totalK, outFeats, uniqOut, n);
}